// Round 9
// baseline (1295.697 us; speedup 1.0000x reference)
//
#include <hip/hip_runtime.h>

#define HID 256
#define AS_LD 72    // u16; K-loop A-tile row stride (144 B, 16B-aligned)
#define TB_LD 264   // u16; epilogue transpose row stride (528 B, 16B-aligned)

typedef unsigned short u16;
typedef unsigned char u8;
typedef unsigned int u32;
typedef short bf16x8 __attribute__((ext_vector_type(8)));
typedef float f32x4 __attribute__((ext_vector_type(4)));
typedef u16 u16x8 __attribute__((ext_vector_type(8)));

static __device__ __forceinline__ float bf2f(u16 b) {
    u32 u = ((u32)b) << 16;
    return __uint_as_float(u);
}
static __device__ __forceinline__ u16 f2bf(float f) {
    u32 u = __float_as_uint(f);
    return (u16)((u + 0x7FFFu + ((u >> 16) & 1u)) >> 16);  // RN-even
}

// ---------------------------------------------------------------------------
// Fused gather + GEMM + relu, tile 64 rows x 256 cols, 512 threads.
// R9: u8 messages with R5's liveness discipline (fixes R8's spill):
//   PAIR LOOP: one staging phase per 128-B line (2 K-chunks), consumed
//   IMMEDIATELY (va dead before any MFMA -- no cross-iteration data
//   liveness, unlike R8), then TWO compute phases from the two LDS buffers.
//   Thread g's 16 B belongs to chunk g>>2 at col (g&3)*16: uniform code,
//   no divergence (R8 idled half the lanes per chunk).
//   Per pair: bqE -> consume -> bqO -> issue(next) -> lgkm+barrier ->
//   computeE [vmcnt(10): bqO+gathers in flight] -> computeO [vmcnt(6):
//   gathers in flight across BOTH phases] -> barrier.
// Kept from R8 (validated): full-line uint4 gathers (1.2M lines/layer,
// half of bf16-R5), per-row fp32 scale loaded once in the preamble,
// per-row quant epilogue (numerics harness-passed in R6/R7/R8).
// launch_bounds (512,4): VGPR cap 128 (R4: lower caps -> catastrophic
// scratch). Peak live ~100 regs (va overlaps bqE only, never bqO/MFMA).
// ---------------------------------------------------------------------------
__global__ __launch_bounds__(512, 4) void fused_layer(
    const u8* __restrict__ Sg, const float* __restrict__ Ssc,
    const int* __restrict__ graph, int c1,
    const u16* __restrict__ Bd, int ldbd, int c2,
    const float* __restrict__ Cf, int ldcf, int Kc, int c3,
    const u16* __restrict__ WB, int ldw,
    const float* __restrict__ bias,
    void* __restrict__ Cout, float* __restrict__ Csc, int M)
{
    __shared__ __align__(16) u16 lds[2 * 64 * AS_LD];   // 18,432 B (union: A-dbuf / transpose)

    const int t    = threadIdx.x;
    const int w    = t >> 6;           // 0..7
    const int lane = t & 63;
    const int row0 = blockIdx.x * 64;
    const int wc   = w * 32;           // wave's 32 columns
    const int fr   = lane & 15;
    const int fq   = lane >> 4;

    const int g  = t & 7;              // granule within row
    const int ra = t >> 3;             // 0..63 -> one A row per thread
    const int gr = row0 + ra;
    const int grc = gr < M ? gr : 0;

    int nbi[6];
    float sv[6];
    const u16* bdp = nullptr;
    if (c1 > 0) {
        const int* gp = graph + (size_t)grc * 6;
        #pragma unroll
        for (int j = 0; j < 6; ++j) nbi[j] = gp[j];
        #pragma unroll
        for (int j = 0; j < 6; ++j) sv[j] = Ssc[nbi[j]];
    }
    if (c2 > 0) bdp = Bd + (size_t)grc * ldbd;

    const int nch   = c1 + c2 + c3;
    const int nbf   = c1 + c2;         // gather + direct-bf16 chunks
    const int npair = c1 >> 1;         // 128-B line pairs (c1 = 0 or 4)

    // prefetch registers
    uint4 va[6];                       // full 128-B pair-line slice (16 B/thread)
    u16x8 vb;                          // direct bf16 chunk
    float fa[8];                       // fp32 chunk

    f32x4 acc[4][2] = {};

    auto issue_pair = [&](int p) {
        #pragma unroll
        for (int j = 0; j < 6; ++j)
            va[j] = *(const uint4*)(Sg + (size_t)nbi[j] * 256 + p * 128 + g * 16);
    };
    auto issue_single = [&](int kc) {
        if (kc < nbf) {
            vb = *(const u16x8*)(bdp + (kc - c1) * 64 + g * 8);
        } else {
            const int kb = (kc - nbf) * 64 + g * 8;
            #pragma unroll
            for (int i = 0; i < 8; ++i)
                fa[i] = (gr < M && kb + i < Kc) ? Cf[(size_t)gr * ldcf + kb + i] : 0.f;
        }
    };

    // consume a staged pair: dequant-sum 16 cols -> bf16 -> LDS buffer g>>2
    // (absolute A col = p*128 + g*16 = chunk (2p + (g>>2)), in-chunk (g&3)*16)
    auto consume_pair = [&]() {
        u16* Ab = lds + (g >> 2) * (64 * AS_LD) + ra * AS_LD + (g & 3) * 16;
        {
            float sa[8] = {};
            #pragma unroll
            for (int j = 0; j < 6; ++j) {
                const u32 lo = va[j].x, hi = va[j].y;
                const float s = sv[j];
                sa[0] += (float)( lo        & 0xFFu) * s;
                sa[1] += (float)((lo >>  8) & 0xFFu) * s;
                sa[2] += (float)((lo >> 16) & 0xFFu) * s;
                sa[3] += (float)( lo >> 24         ) * s;
                sa[4] += (float)( hi        & 0xFFu) * s;
                sa[5] += (float)((hi >>  8) & 0xFFu) * s;
                sa[6] += (float)((hi >> 16) & 0xFFu) * s;
                sa[7] += (float)( hi >> 24         ) * s;
            }
            u16 o[8];
            #pragma unroll
            for (int e = 0; e < 8; ++e) o[e] = f2bf(sa[e]);
            *(uint4*)(Ab) = *(const uint4*)o;
        }
        {
            float sa[8] = {};
            #pragma unroll
            for (int j = 0; j < 6; ++j) {
                const u32 lo = va[j].z, hi = va[j].w;
                const float s = sv[j];
                sa[0] += (float)( lo        & 0xFFu) * s;
                sa[1] += (float)((lo >>  8) & 0xFFu) * s;
                sa[2] += (float)((lo >> 16) & 0xFFu) * s;
                sa[3] += (float)( lo >> 24         ) * s;
                sa[4] += (float)( hi        & 0xFFu) * s;
                sa[5] += (float)((hi >>  8) & 0xFFu) * s;
                sa[6] += (float)((hi >> 16) & 0xFFu) * s;
                sa[7] += (float)( hi >> 24         ) * s;
            }
            u16 o[8];
            #pragma unroll
            for (int e = 0; e < 8; ++e) o[e] = f2bf(sa[e]);
            *(uint4*)(Ab + 8) = *(const uint4*)o;
        }
    };
    auto consume_single = [&](int kc, u16* AbBase) {
        u16 o[8];
        if (kc < nbf) {
            *(u16x8*)o = vb;
        } else {
            #pragma unroll
            for (int i = 0; i < 8; ++i) o[i] = f2bf(fa[i]);
        }
        *(uint4*)(AbBase + ra * AS_LD + g * 8) = *(const uint4*)o;
    };

    auto load_bq = [&](bf16x8 bq[2][2], int kc) {
        #pragma unroll
        for (int s = 0; s < 2; ++s)
            #pragma unroll
            for (int j = 0; j < 2; ++j) {
                const int col = wc + j * 16 + fr;
                bq[s][j] = *(const bf16x8*)(WB + (size_t)col * ldw + kc * 64 + s * 32 + fq * 8);
            }
    };
    auto compute = [&](const u16* Ab, bf16x8 bq[2][2]) {
        #pragma unroll
        for (int s = 0; s < 2; ++s) {
            bf16x8 af[4];
            #pragma unroll
            for (int i = 0; i < 4; ++i)
                af[i] = *(const bf16x8*)(Ab + (i * 16 + fr) * AS_LD + s * 32 + fq * 8);
            #pragma unroll
            for (int j = 0; j < 2; ++j)
                #pragma unroll
                for (int i = 0; i < 4; ++i)
                    acc[i][j] = __builtin_amdgcn_mfma_f32_16x16x32_bf16(bq[s][j], af[i], acc[i][j], 0, 0, 0);
        }
    };

    if (npair > 0) issue_pair(0);
    else if (nch > 0) issue_single(0);   // c1 == 0: first chunk is a single

    #pragma unroll 1
    for (int p = 0; p < npair; ++p) {
        bf16x8 bqE[2][2], bqO[2][2];
        load_bq(bqE, 2 * p);               // oldest this iteration
        consume_pair();                    // waits gathers only (bqE in flight)
        load_bq(bqO, 2 * p + 1);           // older than next gathers
        if (p + 1 < npair) issue_pair(p + 1);
        else if (c1 < nch) issue_single(c1);
        asm volatile("s_waitcnt lgkmcnt(0)" ::: "memory");
        __builtin_amdgcn_s_barrier();
        asm volatile("" ::: "memory");
        compute(lds, bqE);                 // vmcnt(10): bqO + gathers in flight
        compute(lds + 64 * AS_LD, bqO);    // vmcnt(6): gathers still in flight
        __builtin_amdgcn_s_barrier();      // buffers free for overwrite
        asm volatile("" ::: "memory");
    }

    #pragma unroll 1
    for (int kc = c1; kc < nch; ++kc) {
        u16* Ab = lds + ((kc - c1) & 1) * (64 * AS_LD);
        bf16x8 bq[2][2];
        load_bq(bq, kc);
        consume_single(kc, Ab);
        if (kc + 1 < nch) issue_single(kc + 1);
        asm volatile("s_waitcnt lgkmcnt(0)" ::: "memory");
        __builtin_amdgcn_s_barrier();
        asm volatile("" ::: "memory");
        compute(Ab, bq);
    }

    // ---- epilogue: 2-pass transpose through LDS ----
    // acc[i][j]: C-rows i*16+fr, C-cols wc + j*16 + fq*4 .. +3
    u16* Tb = lds;                          // 32 x TB_LD view
    const bool quant = (Csc != nullptr);
    #pragma unroll
    for (int s2 = 0; s2 < 2; ++s2) {
        __syncthreads();                    // K-loop / previous pass done with lds
        #pragma unroll
        for (int j = 0; j < 2; ++j) {
            const int gc = wc + j * 16 + fq * 4;
            float4 bv = make_float4(0.f, 0.f, 0.f, 0.f);
            if (bias) bv = *(const float4*)&bias[gc];
            #pragma unroll
            for (int ii = 0; ii < 2; ++ii) {
                const int i = s2 * 2 + ii;  // acc row-block
                u16 o[4];
                o[0] = f2bf(fmaxf(acc[i][j][0] + bv.x, 0.f));
                o[1] = f2bf(fmaxf(acc[i][j][1] + bv.y, 0.f));
                o[2] = f2bf(fmaxf(acc[i][j][2] + bv.z, 0.f));
                o[3] = f2bf(fmaxf(acc[i][j][3] + bv.w, 0.f));
                *(uint2*)(Tb + (ii * 16 + fr) * TB_LD + gc) = *(const uint2*)o;
            }
        }
        __syncthreads();                    // half-tile complete
        const int gsl = t & 31;             // 8-col granule within 256-col row
        const int rb  = t >> 5;             // 0..15
        #pragma unroll
        for (int it2 = 0; it2 < 2; ++it2) {
            const int rl = it2 * 16 + rb;
            const int grr = row0 + s2 * 32 + rl;
            const u16x8 v = *(const u16x8*)(Tb + rl * TB_LD + gsl * 8);
            if (quant) {
                // per-ROW linear quant: 32-lane row max via shfl tree
                float f[8];
                float mx = 0.f;
                #pragma unroll
                for (int e = 0; e < 8; ++e) { f[e] = bf2f(v[e]); mx = fmaxf(mx, f[e]); }
                mx = fmaxf(mx, __shfl_xor(mx, 1));
                mx = fmaxf(mx, __shfl_xor(mx, 2));
                mx = fmaxf(mx, __shfl_xor(mx, 4));
                mx = fmaxf(mx, __shfl_xor(mx, 8));
                mx = fmaxf(mx, __shfl_xor(mx, 16));
                const float r = mx > 0.f ? 255.f / mx : 0.f;
                u32 plo = 0, phi = 0;
                #pragma unroll
                for (int e = 0; e < 4; ++e)
                    plo |= ((u32)(f[e] * r + 0.5f)) << (8 * e);
                #pragma unroll
                for (int e = 4; e < 8; ++e)
                    phi |= ((u32)(f[e] * r + 0.5f)) << (8 * (e - 4));
                if (grr < M) {
                    uint2 qv; qv.x = plo; qv.y = phi;
                    *(uint2*)((u8*)Cout + (size_t)grr * 256 + gsl * 8) = qv;
                    if (gsl == 0)
                        Csc[grr] = mx * (1.f / 255.f);
                }
            } else {
                if (grr < M)
                    *(u16x8*)((u16*)Cout + (size_t)grr * 256 + gsl * 8) = v;
            }
        }
    }
}

// WB[n][k] bf16: k<k1 -> src1[n][off1+k]; k1<=k<k1+k2 -> src2[n][off2+k-k1]; else 0
__global__ void build_wb(const float* __restrict__ src1, int lds1, int off1, int k1,
                         const float* __restrict__ src2, int lds2, int off2, int k2,
                         u16* __restrict__ dst, int ldd)
{
    const int n = blockIdx.x;  // 0..255
    for (int k = threadIdx.x; k < ldd; k += blockDim.x) {
        float v = 0.f;
        if (k < k1)           v = src1[(size_t)n * lds1 + off1 + k];
        else if (k < k1 + k2) v = src2[(size_t)n * lds2 + off2 + (k - k1)];
        dst[(size_t)n * ldd + k] = f2bf(v);
    }
}

// FB[e][0:64] = bf16(fbonds[e][0:50]) padded with zeros
__global__ void build_fb(const float* __restrict__ fb, u16* __restrict__ FB, int E)
{
    const int e = blockIdx.x * 4 + (threadIdx.x >> 6);
    if (e >= E) return;
    const int k = threadIdx.x & 63;
    FB[(size_t)e * 64 + k] = (k < 50) ? f2bf(fb[(size_t)e * 50 + k]) : (u16)0;
}

// per-molecule mean over sorted mol_ids; atomh bf16, out fp32
__global__ void segment_mean(const u16* __restrict__ atomh, const int* __restrict__ mol_ids,
                             float* __restrict__ out, int N)
{
    const int m = blockIdx.x;
    const int t = threadIdx.x;
    __shared__ int s_lo, s_hi;
    if (t == 0) {
        int lo = 0, hi = N;
        while (lo < hi) { int mid = (lo + hi) >> 1; if (mol_ids[mid] < m) lo = mid + 1; else hi = mid; }
        s_lo = lo;
        lo = s_lo; hi = N;
        while (lo < hi) { int mid = (lo + hi) >> 1; if (mol_ids[mid] < m + 1) lo = mid + 1; else hi = mid; }
        s_hi = lo;
    }
    __syncthreads();
    const int lo = s_lo, hi = s_hi;
    float sum = 0.f;
    for (int a = lo; a < hi; ++a) sum += bf2f(atomh[(size_t)a * HID + t]);
    const float cnt = (float)((hi - lo) > 1 ? (hi - lo) : 1);
    out[(size_t)m * HID + t] = sum / cnt;
}

extern "C" void kernel_launch(void* const* d_in, const int* in_sizes, int n_in,
                              void* d_out, int out_size, void* d_ws, size_t ws_size,
                              hipStream_t stream)
{
    const float* fatoms = (const float*)d_in[0];
    const float* fbonds = (const float*)d_in[1];
    const int*   agraph = (const int*)d_in[2];
    const int*   bgraph = (const int*)d_in[3];
    const int*   mol_ids = (const int*)d_in[4];
    const float* W_i = (const float*)d_in[7];
    const float* W_h = (const float*)d_in[8];
    const float* W_o = (const float*)d_in[9];
    const float* b_o = (const float*)d_in[10];

    const int N = in_sizes[0] / 39;       // 100000
    const int E = in_sizes[1] / 50;       // 200001
    const int N_MOLS = 1000;
    const int DEPTH = 6;

    // workspace layout (bytes); all section sizes multiples of 256
    const size_t q_sz  = (size_t)E * 256;                      // u8 messages [E][256]
    const size_t sc_sz = (((size_t)E * 4) + 255) & ~(size_t)255;  // fp32 scales [E]
    const size_t fb_sz = (size_t)E * 64 * 2;                   // bf16 FB [E][64]
    const size_t ah_sz = (size_t)N * HID * 2;                  // bf16 atom_hiddens
    const size_t wbh_sz = (size_t)256 * 320 * 2;
    const size_t wbi_sz = (size_t)256 * 64 * 2;
    const size_t wbo_sz = (size_t)256 * 320 * 2;
    const size_t need = 2 * q_sz + 2 * sc_sz + fb_sz + ah_sz + wbh_sz + wbi_sz + wbo_sz;
    if (ws_size < need) return;

    u8* p = (u8*)d_ws;
    u8*    q0  = p;             p += q_sz;
    u8*    q1  = p;             p += q_sz;
    float* sc0 = (float*)p;     p += sc_sz;
    float* sc1 = (float*)p;     p += sc_sz;
    u16*   FB  = (u16*)p;       p += fb_sz;
    u16*   ah  = (u16*)p;       p += ah_sz;
    u16*   wbh = (u16*)p;       p += wbh_sz;
    u16*   wbi = (u16*)p;       p += wbi_sz;
    u16*   wbo = (u16*)p;

    float* out = (float*)d_out;

    build_wb<<<dim3(256), dim3(64), 0, stream>>>(W_h, 256, 0, 256, W_i, 50, 0, 50, wbh, 320);
    build_wb<<<dim3(256), dim3(64), 0, stream>>>(W_i, 50, 0, 50, W_i, 50, 0, 0, wbi, 64);
    build_wb<<<dim3(256), dim3(64), 0, stream>>>(W_o, 295, 39, 256, W_o, 295, 0, 39, wbo, 320);
    build_fb<<<dim3((E + 3) / 4), dim3(256), 0, stream>>>(fbonds, FB, E);

    const int gE = (E + 63) / 64;     // 3126
    const int gN = (N + 63) / 64;     // 1563

    // layer 0: q0 = quant(relu(FB @ W_i.T))
    fused_layer<<<dim3(gE), dim3(512), 0, stream>>>(
        nullptr, nullptr, nullptr, 0, FB, 64, 1, nullptr, 0, 0, 0,
        wbi, 64, nullptr, q0, sc0, E);

    // hidden layers (ping-pong): dst = quant(relu(gather(src)@W_h.T + fbonds@W_i.T))
    u8* src = q0;  float* ssc = sc0;
    u8* dst = q1;  float* dsc = sc1;
    for (int it = 0; it < DEPTH - 1; ++it) {
        fused_layer<<<dim3(gE), dim3(512), 0, stream>>>(
            src, ssc, bgraph, 4, FB, 64, 1, nullptr, 0, 0, 0,
            wbh, 320, nullptr, dst, dsc, E);
        u8* tq = src; src = dst; dst = tq;
        float* ts = ssc; ssc = dsc; dsc = ts;
    }
    // after 5 layers: src/ssc = final message

    // output layer: ah = relu(gather_a(src)@W_o[:,39:].T + fatoms@W_o[:,:39].T + b_o), bf16
    fused_layer<<<dim3(gN), dim3(512), 0, stream>>>(
        src, ssc, agraph, 4, nullptr, 0, 0, fatoms, 39, 39, 1,
        wbo, 320, b_o, ah, nullptr, N);

    // per-molecule mean
    segment_mean<<<dim3(N_MOLS), dim3(256), 0, stream>>>(ah, mol_ids, out, N);
}

// Round 10
// 914.320 us; speedup vs baseline: 1.4171x; 1.4171x over previous
//
#include <hip/hip_runtime.h>

#define HID 256
#define AS_LD 72    // u16; K-loop A-tile row stride (144 B)
#define TB_LD 264   // u16; epilogue transpose row stride (528 B, 16B-aligned)

typedef unsigned short u16;
typedef unsigned int u32;
typedef short bf16x8 __attribute__((ext_vector_type(8)));
typedef float f32x4 __attribute__((ext_vector_type(4)));
typedef u16 u16x8 __attribute__((ext_vector_type(8)));

static __device__ __forceinline__ float bf2f(u16 b) {
    u32 u = ((u32)b) << 16;
    return __uint_as_float(u);
}
static __device__ __forceinline__ u16 f2bf(float f) {
    u32 u = __float_as_uint(f);
    return (u16)((u + 0x7FFFu + ((u >> 16) & 1u)) >> 16);  // RN-even
}

// ---------------------------------------------------------------------------
// Fused gather + GEMM + relu, tile 64 rows x 256 cols, BK=64, 512 threads.
// R10 = exact revert to the verified-best R5 state (914.6 us total,
// hidden layers 133 us, VGPR 64 no-spill, FETCH 314 MB, WRITE 106 MB).
// The u8-message arc (R6-R9) is closed: 3 structural variants all spilled
// (WRITE 923/244/363 MB) -- the dequant path's live state cannot fit the
// 128-reg unified budget at 4 waves/SIMD alongside acc+bq+prefetch.
// Chunked bf16 staging + software pipeline with issue-order discipline:
//   per chunk kc:
//     1. bq loads (WB B-frags, L2-hot)   <- oldest this iteration
//     2. consume(kc): vmcnt waits for gather kc only (bq in flight),
//        fp32 sum -> bf16 -> LDS (double-buffered A-tile)
//     3. issue(kc+1): 6 gather loads     <- youngest; stay in flight
//     4. s_waitcnt lgkmcnt(0) + raw s_barrier (no vmcnt drain)
//     5. ds_read af + 16 MFMAs (bq wait = counted vmcnt; kc+1 gathers
//        remain outstanding across barrier + compute)
// Cache policy: all accesses cacheable (R5 A/B vs R3's NT stores: 144->133).
// launch_bounds (512,4): the proven no-spill envelope (R4: (512,6) -> 40
// VGPR cap -> 1.4 GB scratch).
// ---------------------------------------------------------------------------
__global__ __launch_bounds__(512, 4) void fused_layer(
    const u16* __restrict__ Sg, const int* __restrict__ graph, int c1,
    const u16* __restrict__ Bd, int ldbd, int c2,
    const float* __restrict__ Cf, int ldcf, int Kc, int c3,
    const u16* __restrict__ WB, int ldw,
    const float* __restrict__ bias,
    u16* __restrict__ C, int M)
{
    __shared__ __align__(16) u16 lds[2 * 64 * AS_LD];   // 18,432 B (union: A-dbuf / transpose)

    const int t    = threadIdx.x;
    const int w    = t >> 6;           // 0..7
    const int lane = t & 63;
    const int row0 = blockIdx.x * 64;
    const int wc   = w * 32;           // wave's 32 columns
    const int fr   = lane & 15;
    const int fq   = lane >> 4;

    const int g  = t & 7;              // 16B granule within 128B row-chunk
    const int ra = t >> 3;             // 0..63 -> one row per thread
    const int gr = row0 + ra;
    const int grc = gr < M ? gr : 0;

    int nbi[6];
    const u16* bdp = nullptr;
    if (c1 > 0) {
        const int* gp = graph + (size_t)grc * 6;
        #pragma unroll
        for (int j = 0; j < 6; ++j) nbi[j] = gp[j];
    }
    if (c2 > 0) bdp = Bd + (size_t)grc * ldbd;

    const int nch = c1 + c2 + c3;
    const int nbf = c1 + c2;           // bf16-typed chunks

    // prefetch registers (chunk kc in flight while chunk kc-1 computes)
    u16x8 va[6];
    float fa[8];

    // issue global loads for chunk kc (register destinations, non-blocking)
    auto issue = [&](int kc) {
        if (kc < c1) {
            #pragma unroll
            for (int j = 0; j < 6; ++j)
                va[j] = *(const u16x8*)(Sg + (size_t)nbi[j] * 256 + kc * 64 + g * 8);
        } else if (kc < nbf) {
            va[0] = *(const u16x8*)(bdp + (kc - c1) * 64 + g * 8);
        } else {
            const int kb = (kc - nbf) * 64 + g * 8;
            #pragma unroll
            for (int i = 0; i < 8; ++i)
                fa[i] = (gr < M && kb + i < Kc) ? Cf[(size_t)gr * ldcf + kb + i] : 0.f;
        }
    };

    // consume in-flight loads for chunk kc -> bf16 row fragment -> LDS
    auto consume = [&](int kc, u16* Ab) {
        u16 o[8];
        if (kc < c1) {
            float sa[8] = {};
            #pragma unroll
            for (int j = 0; j < 6; ++j)
                #pragma unroll
                for (int e = 0; e < 8; ++e) sa[e] += bf2f(va[j][e]);
            #pragma unroll
            for (int e = 0; e < 8; ++e) o[e] = f2bf(sa[e]);
        } else if (kc < nbf) {
            *(u16x8*)o = va[0];
        } else {
            #pragma unroll
            for (int i = 0; i < 8; ++i) o[i] = f2bf(fa[i]);
        }
        *(uint4*)(Ab + ra * AS_LD + g * 8) = *(const uint4*)o;
    };

    f32x4 acc[4][2] = {};
    issue(0);
    #pragma unroll 1
    for (int kc = 0; kc < nch; ++kc) {
        u16* Ab = lds + (kc & 1) * (64 * AS_LD);

        // 1. B fragments for this chunk FIRST (older than the prefetch, so
        //    the compute phase needs only a counted vmcnt wait for them)
        bf16x8 bq[2][2];
        #pragma unroll
        for (int s = 0; s < 2; ++s)
            #pragma unroll
            for (int j = 0; j < 2; ++j) {
                const int col = wc + j * 16 + fr;
                bq[s][j] = *(const bf16x8*)(WB + (size_t)col * ldw + kc * 64 + s * 32 + fq * 8);
            }

        // 2. consume chunk kc (waits for its gathers; bq still in flight)
        consume(kc, Ab);

        // 3. prefetch chunk kc+1 (youngest; stays outstanding across
        //    barrier + compute + next iteration's bq/consume)
        if (kc + 1 < nch) issue(kc + 1);

        // 4. drain LDS writes only; global prefetch stays outstanding
        asm volatile("s_waitcnt lgkmcnt(0)" ::: "memory");
        __builtin_amdgcn_s_barrier();
        asm volatile("" ::: "memory");   // fence: no memory-op hoist above barrier

        // 5. compute: ds_read A frags + 16 MFMAs (bq wait = counted vmcnt)
        #pragma unroll
        for (int s = 0; s < 2; ++s) {
            bf16x8 af[4];
            #pragma unroll
            for (int i = 0; i < 4; ++i)
                af[i] = *(const bf16x8*)(Ab + (i * 16 + fr) * AS_LD + s * 32 + fq * 8);
            #pragma unroll
            for (int j = 0; j < 2; ++j)
                #pragma unroll
                for (int i = 0; i < 4; ++i)
                    acc[i][j] = __builtin_amdgcn_mfma_f32_16x16x32_bf16(bq[s][j], af[i], acc[i][j], 0, 0, 0);
        }
    }

    // ---- epilogue: 2-pass transpose through LDS, full-line cacheable stores
    // (dst is gather-read by the NEXT layer -> keep it in L2/L3)
    // acc[i][j]: C-rows i*16+fr, C-cols wc + j*16 + fq*4 .. +3
    u16* Tb = lds;                          // 32 x TB_LD view
    #pragma unroll
    for (int s2 = 0; s2 < 2; ++s2) {
        __syncthreads();                    // K-loop / previous pass done with lds
        #pragma unroll
        for (int j = 0; j < 2; ++j) {
            const int gc = wc + j * 16 + fq * 4;
            float4 bv = make_float4(0.f, 0.f, 0.f, 0.f);
            if (bias) bv = *(const float4*)&bias[gc];
            #pragma unroll
            for (int ii = 0; ii < 2; ++ii) {
                const int i = s2 * 2 + ii;  // acc row-block
                u16 o[4];
                o[0] = f2bf(fmaxf(acc[i][j][0] + bv.x, 0.f));
                o[1] = f2bf(fmaxf(acc[i][j][1] + bv.y, 0.f));
                o[2] = f2bf(fmaxf(acc[i][j][2] + bv.z, 0.f));
                o[3] = f2bf(fmaxf(acc[i][j][3] + bv.w, 0.f));
                *(uint2*)(Tb + (ii * 16 + fr) * TB_LD + gc) = *(const uint2*)o;
            }
        }
        __syncthreads();                    // half-tile complete
        const int gsl = t & 31;             // 16B granule within 512B row
        const int rb  = t >> 5;             // 0..15
        #pragma unroll
        for (int it2 = 0; it2 < 2; ++it2) {
            const int rl = it2 * 16 + rb;
            const int grr = row0 + s2 * 32 + rl;
            if (grr < M) {
                const u16x8 v = *(const u16x8*)(Tb + rl * TB_LD + gsl * 8);
                *(u16x8*)(C + (size_t)grr * 256 + gsl * 8) = v;
            }
        }
    }
}

// WB[n][k] bf16: k<k1 -> src1[n][off1+k]; k1<=k<k1+k2 -> src2[n][off2+k-k1]; else 0
__global__ void build_wb(const float* __restrict__ src1, int lds1, int off1, int k1,
                         const float* __restrict__ src2, int lds2, int off2, int k2,
                         u16* __restrict__ dst, int ldd)
{
    const int n = blockIdx.x;  // 0..255
    for (int k = threadIdx.x; k < ldd; k += blockDim.x) {
        float v = 0.f;
        if (k < k1)           v = src1[(size_t)n * lds1 + off1 + k];
        else if (k < k1 + k2) v = src2[(size_t)n * lds2 + off2 + (k - k1)];
        dst[(size_t)n * ldd + k] = f2bf(v);
    }
}

// FB[e][0:64] = bf16(fbonds[e][0:50]) padded with zeros
__global__ void build_fb(const float* __restrict__ fb, u16* __restrict__ FB, int E)
{
    const int e = blockIdx.x * 4 + (threadIdx.x >> 6);
    if (e >= E) return;
    const int k = threadIdx.x & 63;
    FB[(size_t)e * 64 + k] = (k < 50) ? f2bf(fb[(size_t)e * 50 + k]) : (u16)0;
}

// per-molecule mean over sorted mol_ids; atomh bf16, out fp32
__global__ void segment_mean(const u16* __restrict__ atomh, const int* __restrict__ mol_ids,
                             float* __restrict__ out, int N)
{
    const int m = blockIdx.x;
    const int t = threadIdx.x;
    __shared__ int s_lo, s_hi;
    if (t == 0) {
        int lo = 0, hi = N;
        while (lo < hi) { int mid = (lo + hi) >> 1; if (mol_ids[mid] < m) lo = mid + 1; else hi = mid; }
        s_lo = lo;
        lo = s_lo; hi = N;
        while (lo < hi) { int mid = (lo + hi) >> 1; if (mol_ids[mid] < m + 1) lo = mid + 1; else hi = mid; }
        s_hi = lo;
    }
    __syncthreads();
    const int lo = s_lo, hi = s_hi;
    float sum = 0.f;
    for (int a = lo; a < hi; ++a) sum += bf2f(atomh[(size_t)a * HID + t]);
    const float cnt = (float)((hi - lo) > 1 ? (hi - lo) : 1);
    out[(size_t)m * HID + t] = sum / cnt;
}

extern "C" void kernel_launch(void* const* d_in, const int* in_sizes, int n_in,
                              void* d_out, int out_size, void* d_ws, size_t ws_size,
                              hipStream_t stream)
{
    const float* fatoms = (const float*)d_in[0];
    const float* fbonds = (const float*)d_in[1];
    const int*   agraph = (const int*)d_in[2];
    const int*   bgraph = (const int*)d_in[3];
    const int*   mol_ids = (const int*)d_in[4];
    const float* W_i = (const float*)d_in[7];
    const float* W_h = (const float*)d_in[8];
    const float* W_o = (const float*)d_in[9];
    const float* b_o = (const float*)d_in[10];

    const int N = in_sizes[0] / 39;       // 100000
    const int E = in_sizes[1] / 50;       // 200001
    const int N_MOLS = 1000;
    const int DEPTH = 6;

    const size_t EH = (size_t)E * HID;
    const size_t wbh_sz = (size_t)256 * 320;
    const size_t wbi_sz = (size_t)256 * 64;
    const size_t wbo_sz = (size_t)256 * 320;
    const size_t wsz = wbh_sz + wbi_sz + wbo_sz;
    const size_t fb_sz = (size_t)E * 64;

    const size_t need_nofb = (2 * EH + wsz) * sizeof(u16);
    const size_t need_fb   = (2 * EH + fb_sz + wsz) * sizeof(u16);
    if (ws_size < need_nofb) return;
    const bool use_fb = (ws_size >= need_fb);

    u16* buf0 = (u16*)d_ws;                       // [E][256]
    u16* buf1 = buf0 + EH;                        // [E][256]
    u16* FB   = use_fb ? (buf1 + EH) : nullptr;   // [E][64] bf16 fbonds
    u16* wbh  = (use_fb ? FB + fb_sz : buf1 + EH);
    u16* wbi  = wbh + wbh_sz;
    u16* wbo  = wbi + wbi_sz;

    float* out = (float*)d_out;

    build_wb<<<dim3(256), dim3(64), 0, stream>>>(W_h, 256, 0, 256, W_i, 50, 0, 50, wbh, 320);
    build_wb<<<dim3(256), dim3(64), 0, stream>>>(W_i, 50, 0, 50, W_i, 50, 0, 0, wbi, 64);
    build_wb<<<dim3(256), dim3(64), 0, stream>>>(W_o, 295, 39, 256, W_o, 295, 0, 39, wbo, 320);
    if (use_fb)
        build_fb<<<dim3((E + 3) / 4), dim3(256), 0, stream>>>(fbonds, FB, E);

    const int gE = (E + 63) / 64;     // 3126
    const int gN = (N + 63) / 64;     // 1563

    // layer 0: buf0 = relu(fbonds @ W_i.T)
    if (use_fb)
        fused_layer<<<dim3(gE), dim3(512), 0, stream>>>(
            nullptr, nullptr, 0, FB, 64, 1, nullptr, 0, 0, 0, wbi, 64, nullptr, buf0, E);
    else
        fused_layer<<<dim3(gE), dim3(512), 0, stream>>>(
            nullptr, nullptr, 0, nullptr, 0, 0, fbonds, 50, 50, 1, wbi, 64, nullptr, buf0, E);

    // hidden layers (ping-pong): dst = relu(gather(src)@W_h.T + fbonds@W_i.T)
    u16* src = buf0;
    u16* dst = buf1;
    for (int it = 0; it < DEPTH - 1; ++it) {
        if (use_fb)
            fused_layer<<<dim3(gE), dim3(512), 0, stream>>>(
                src, bgraph, 4, FB, 64, 1, nullptr, 0, 0, 0, wbh, 320, nullptr, dst, E);
        else
            fused_layer<<<dim3(gE), dim3(512), 0, stream>>>(
                src, bgraph, 4, nullptr, 0, 0, fbonds, 50, 50, 1, wbh, 320, nullptr, dst, E);
        u16* tmp = src; src = dst; dst = tmp;
    }
    // after 5 layers: src = buf1 (final message), dst = buf0 (free)

    // output layer: dst = relu(gather_a(src)@W_o[:,39:].T + fatoms@W_o[:,:39].T + b_o)
    fused_layer<<<dim3(gN), dim3(512), 0, stream>>>(
        src, agraph, 4, nullptr, 0, 0, fatoms, 39, 39, 1, wbo, 320, b_o, dst, N);

    // per-molecule mean
    segment_mean<<<dim3(N_MOLS), dim3(256), 0, stream>>>(dst, mol_ids, out, N);
}

// Round 11
// 871.387 us; speedup vs baseline: 1.4869x; 1.0493x over previous
//
#include <hip/hip_runtime.h>

#define HID 256
#define AS_LD 72    // u16; K-loop A-tile row stride (144 B)
#define TB_LD 264   // u16; epilogue transpose row stride (528 B, 16B-aligned)

typedef unsigned short u16;
typedef unsigned int u32;
typedef short bf16x8 __attribute__((ext_vector_type(8)));
typedef float f32x4 __attribute__((ext_vector_type(4)));
typedef u16 u16x8 __attribute__((ext_vector_type(8)));

static __device__ __forceinline__ float bf2f(u16 b) {
    u32 u = ((u32)b) << 16;
    return __uint_as_float(u);
}
static __device__ __forceinline__ u16 f2bf(float f) {
    u32 u = __float_as_uint(f);
    return (u16)((u + 0x7FFFu + ((u >> 16) & 1u)) >> 16);  // RN-even
}

// ---------------------------------------------------------------------------
// Fused gather + GEMM + relu, tile 64 rows x 256 cols, BK=64, 512 threads.
// R11 = R10's verified K-loop (914.3 us; hidden 133.7 us, VGPR 64, no spill)
// + FUSED PER-MOLECULE MEAN in the output layer's epilogue:
//   mol_ids is SORTED, so a 64-row tile spans 1-3 contiguous molecules.
//   When Msum != nullptr the epilogue skips the 51 MB atom_hiddens store;
//   instead each thread owns one column, walks its 16 rows of the transpose
//   tile serially from LDS (molecule boundaries are wave-uniform: all lanes
//   share the same row sequence), and flushes one fp32 atomicAdd per
//   molecule segment (~2 atomics per molecule-column total, G12-compliant).
//   Eliminates: 51 MB ah write + 51 MB segment_mean re-read + its launch.
// K-loop (untouched, R5-verified): chunked bf16 staging, software pipeline
// with issue-order discipline:
//   1. bq loads (WB B-frags, L2-hot)   <- oldest this iteration
//   2. consume(kc): vmcnt waits for gather kc only (bq in flight)
//   3. issue(kc+1) gathers             <- youngest; stay in flight
//   4. s_waitcnt lgkmcnt(0) + raw s_barrier (no vmcnt drain)
//   5. ds_read af + 16 MFMAs (bq wait = counted vmcnt)
// launch_bounds (512,4): the proven no-spill envelope (R4/R6-R9 lessons).
// ---------------------------------------------------------------------------
__global__ __launch_bounds__(512, 4) void fused_layer(
    const u16* __restrict__ Sg, const int* __restrict__ graph, int c1,
    const u16* __restrict__ Bd, int ldbd, int c2,
    const float* __restrict__ Cf, int ldcf, int Kc, int c3,
    const u16* __restrict__ WB, int ldw,
    const float* __restrict__ bias,
    u16* __restrict__ C, int M,
    const int* __restrict__ amol, float* __restrict__ Msum)
{
    __shared__ __align__(16) u16 lds[2 * 64 * AS_LD];   // 18,432 B (union: A-dbuf / transpose)
    __shared__ int smol[64];                            // molecule id per tile row

    const int t    = threadIdx.x;
    const int w    = t >> 6;           // 0..7
    const int lane = t & 63;
    const int row0 = blockIdx.x * 64;
    const int wc   = w * 32;           // wave's 32 columns
    const int fr   = lane & 15;
    const int fq   = lane >> 4;

    const int g  = t & 7;              // 16B granule within 128B row-chunk
    const int ra = t >> 3;             // 0..63 -> one row per thread
    const int gr = row0 + ra;
    const int grc = gr < M ? gr : 0;

    if (Msum != nullptr && t < 64)
        smol[t] = (row0 + t < M) ? amol[row0 + t] : -1;

    int nbi[6];
    const u16* bdp = nullptr;
    if (c1 > 0) {
        const int* gp = graph + (size_t)grc * 6;
        #pragma unroll
        for (int j = 0; j < 6; ++j) nbi[j] = gp[j];
    }
    if (c2 > 0) bdp = Bd + (size_t)grc * ldbd;

    const int nch = c1 + c2 + c3;
    const int nbf = c1 + c2;           // bf16-typed chunks

    // prefetch registers (chunk kc in flight while chunk kc-1 computes)
    u16x8 va[6];
    float fa[8];

    // issue global loads for chunk kc (register destinations, non-blocking)
    auto issue = [&](int kc) {
        if (kc < c1) {
            #pragma unroll
            for (int j = 0; j < 6; ++j)
                va[j] = *(const u16x8*)(Sg + (size_t)nbi[j] * 256 + kc * 64 + g * 8);
        } else if (kc < nbf) {
            va[0] = *(const u16x8*)(bdp + (kc - c1) * 64 + g * 8);
        } else {
            const int kb = (kc - nbf) * 64 + g * 8;
            #pragma unroll
            for (int i = 0; i < 8; ++i)
                fa[i] = (gr < M && kb + i < Kc) ? Cf[(size_t)gr * ldcf + kb + i] : 0.f;
        }
    };

    // consume in-flight loads for chunk kc -> bf16 row fragment -> LDS
    auto consume = [&](int kc, u16* Ab) {
        u16 o[8];
        if (kc < c1) {
            float sa[8] = {};
            #pragma unroll
            for (int j = 0; j < 6; ++j)
                #pragma unroll
                for (int e = 0; e < 8; ++e) sa[e] += bf2f(va[j][e]);
            #pragma unroll
            for (int e = 0; e < 8; ++e) o[e] = f2bf(sa[e]);
        } else if (kc < nbf) {
            *(u16x8*)o = va[0];
        } else {
            #pragma unroll
            for (int i = 0; i < 8; ++i) o[i] = f2bf(fa[i]);
        }
        *(uint4*)(Ab + ra * AS_LD + g * 8) = *(const uint4*)o;
    };

    f32x4 acc[4][2] = {};
    issue(0);
    #pragma unroll 1
    for (int kc = 0; kc < nch; ++kc) {
        u16* Ab = lds + (kc & 1) * (64 * AS_LD);

        // 1. B fragments for this chunk FIRST (older than the prefetch, so
        //    the compute phase needs only a counted vmcnt wait for them)
        bf16x8 bq[2][2];
        #pragma unroll
        for (int s = 0; s < 2; ++s)
            #pragma unroll
            for (int j = 0; j < 2; ++j) {
                const int col = wc + j * 16 + fr;
                bq[s][j] = *(const bf16x8*)(WB + (size_t)col * ldw + kc * 64 + s * 32 + fq * 8);
            }

        // 2. consume chunk kc (waits for its gathers; bq still in flight)
        consume(kc, Ab);

        // 3. prefetch chunk kc+1 (youngest; stays outstanding across
        //    barrier + compute + next iteration's bq/consume)
        if (kc + 1 < nch) issue(kc + 1);

        // 4. drain LDS writes only; global prefetch stays outstanding
        asm volatile("s_waitcnt lgkmcnt(0)" ::: "memory");
        __builtin_amdgcn_s_barrier();
        asm volatile("" ::: "memory");   // fence: no memory-op hoist above barrier

        // 5. compute: ds_read A frags + 16 MFMAs (bq wait = counted vmcnt)
        #pragma unroll
        for (int s = 0; s < 2; ++s) {
            bf16x8 af[4];
            #pragma unroll
            for (int i = 0; i < 4; ++i)
                af[i] = *(const bf16x8*)(Ab + (i * 16 + fr) * AS_LD + s * 32 + fq * 8);
            #pragma unroll
            for (int j = 0; j < 2; ++j)
                #pragma unroll
                for (int i = 0; i < 4; ++i)
                    acc[i][j] = __builtin_amdgcn_mfma_f32_16x16x32_bf16(bq[s][j], af[i], acc[i][j], 0, 0, 0);
        }
    }

    // ---- epilogue: 2-pass transpose through LDS ----
    // acc[i][j]: C-rows i*16+fr, C-cols wc + j*16 + fq*4 .. +3
    u16* Tb = lds;                          // 32 x TB_LD view
    #pragma unroll
    for (int s2 = 0; s2 < 2; ++s2) {
        __syncthreads();                    // K-loop / previous pass done with lds
        #pragma unroll
        for (int j = 0; j < 2; ++j) {
            const int gc = wc + j * 16 + fq * 4;
            float4 bv = make_float4(0.f, 0.f, 0.f, 0.f);
            if (bias) bv = *(const float4*)&bias[gc];
            #pragma unroll
            for (int ii = 0; ii < 2; ++ii) {
                const int i = s2 * 2 + ii;  // acc row-block
                u16 o[4];
                o[0] = f2bf(fmaxf(acc[i][j][0] + bv.x, 0.f));
                o[1] = f2bf(fmaxf(acc[i][j][1] + bv.y, 0.f));
                o[2] = f2bf(fmaxf(acc[i][j][2] + bv.z, 0.f));
                o[3] = f2bf(fmaxf(acc[i][j][3] + bv.w, 0.f));
                *(uint2*)(Tb + (ii * 16 + fr) * TB_LD + gc) = *(const uint2*)o;
            }
        }
        __syncthreads();                    // half-tile complete
        if (Msum == nullptr) {
            // store path (layer0 / hidden layers): full-line cacheable stores
            // (dst is gather-read by the NEXT layer -> keep it in L2/L3)
            const int gsl = t & 31;         // 16B granule within 512B row
            const int rb  = t >> 5;         // 0..15
            #pragma unroll
            for (int it2 = 0; it2 < 2; ++it2) {
                const int rl = it2 * 16 + rb;
                const int grr = row0 + s2 * 32 + rl;
                if (grr < M) {
                    const u16x8 v = *(const u16x8*)(Tb + rl * TB_LD + gsl * 8);
                    *(u16x8*)(C + (size_t)grr * 256 + gsl * 8) = v;
                }
            }
        } else {
            // fused per-molecule partial sum (output layer): thread owns one
            // column, walks 16 rows serially; mol boundaries are wave-uniform
            // (all lanes share the same row sequence) -> no divergence.
            const int col = t & 255;
            const int h   = t >> 8;         // 0/1: row half of this 32-row tile
            float s = 0.f;
            int cur = -1;
            #pragma unroll 1
            for (int r = h * 16; r < h * 16 + 16; ++r) {
                const int m = smol[s2 * 32 + r];
                if (m != cur) {
                    if (cur >= 0 && s != 0.f)
                        atomicAdd(&Msum[(size_t)cur * HID + col], s);
                    cur = m; s = 0.f;
                }
                if (m >= 0) s += bf2f(Tb[r * TB_LD + col]);
            }
            if (cur >= 0 && s != 0.f)
                atomicAdd(&Msum[(size_t)cur * HID + col], s);
        }
    }
}

// WB[n][k] bf16: k<k1 -> src1[n][off1+k]; k1<=k<k1+k2 -> src2[n][off2+k-k1]; else 0
__global__ void build_wb(const float* __restrict__ src1, int lds1, int off1, int k1,
                         const float* __restrict__ src2, int lds2, int off2, int k2,
                         u16* __restrict__ dst, int ldd)
{
    const int n = blockIdx.x;  // 0..255
    for (int k = threadIdx.x; k < ldd; k += blockDim.x) {
        float v = 0.f;
        if (k < k1)           v = src1[(size_t)n * lds1 + off1 + k];
        else if (k < k1 + k2) v = src2[(size_t)n * lds2 + off2 + (k - k1)];
        dst[(size_t)n * ldd + k] = f2bf(v);
    }
}

// FB[e][0:64] = bf16(fbonds[e][0:50]) padded with zeros
__global__ void build_fb(const float* __restrict__ fb, u16* __restrict__ FB, int E)
{
    const int e = blockIdx.x * 4 + (threadIdx.x >> 6);
    if (e >= E) return;
    const int k = threadIdx.x & 63;
    FB[(size_t)e * 64 + k] = (k < 50) ? f2bf(fb[(size_t)e * 50 + k]) : (u16)0;
}

// out[m][:] /= count(m); counts from sorted mol_ids via binary search
__global__ void normalize_out(const int* __restrict__ mol_ids, float* __restrict__ out, int N)
{
    const int m = blockIdx.x;
    const int t = threadIdx.x;
    __shared__ int s_lo, s_hi;
    if (t == 0) {
        int lo = 0, hi = N;
        while (lo < hi) { int mid = (lo + hi) >> 1; if (mol_ids[mid] < m) lo = mid + 1; else hi = mid; }
        s_lo = lo;
        lo = s_lo; hi = N;
        while (lo < hi) { int mid = (lo + hi) >> 1; if (mol_ids[mid] < m + 1) lo = mid + 1; else hi = mid; }
        s_hi = lo;
    }
    __syncthreads();
    const int cnt = (s_hi - s_lo) > 1 ? (s_hi - s_lo) : 1;
    out[(size_t)m * HID + t] *= (1.f / (float)cnt);
}

extern "C" void kernel_launch(void* const* d_in, const int* in_sizes, int n_in,
                              void* d_out, int out_size, void* d_ws, size_t ws_size,
                              hipStream_t stream)
{
    const float* fatoms = (const float*)d_in[0];
    const float* fbonds = (const float*)d_in[1];
    const int*   agraph = (const int*)d_in[2];
    const int*   bgraph = (const int*)d_in[3];
    const int*   mol_ids = (const int*)d_in[4];
    const float* W_i = (const float*)d_in[7];
    const float* W_h = (const float*)d_in[8];
    const float* W_o = (const float*)d_in[9];
    const float* b_o = (const float*)d_in[10];

    const int N = in_sizes[0] / 39;       // 100000
    const int E = in_sizes[1] / 50;       // 200001
    const int N_MOLS = 1000;
    const int DEPTH = 6;

    const size_t EH = (size_t)E * HID;
    const size_t wbh_sz = (size_t)256 * 320;
    const size_t wbi_sz = (size_t)256 * 64;
    const size_t wbo_sz = (size_t)256 * 320;
    const size_t wsz = wbh_sz + wbi_sz + wbo_sz;
    const size_t fb_sz = (size_t)E * 64;

    const size_t need_nofb = (2 * EH + wsz) * sizeof(u16);
    const size_t need_fb   = (2 * EH + fb_sz + wsz) * sizeof(u16);
    if (ws_size < need_nofb) return;
    const bool use_fb = (ws_size >= need_fb);

    u16* buf0 = (u16*)d_ws;                       // [E][256]
    u16* buf1 = buf0 + EH;                        // [E][256]
    u16* FB   = use_fb ? (buf1 + EH) : nullptr;   // [E][64] bf16 fbonds
    u16* wbh  = (use_fb ? FB + fb_sz : buf1 + EH);
    u16* wbi  = wbh + wbh_sz;
    u16* wbo  = wbi + wbi_sz;

    float* out = (float*)d_out;

    // zero the molecule-sum accumulator (atomicAdd target)
    hipMemsetAsync(out, 0, (size_t)N_MOLS * HID * sizeof(float), stream);

    build_wb<<<dim3(256), dim3(64), 0, stream>>>(W_h, 256, 0, 256, W_i, 50, 0, 50, wbh, 320);
    build_wb<<<dim3(256), dim3(64), 0, stream>>>(W_i, 50, 0, 50, W_i, 50, 0, 0, wbi, 64);
    build_wb<<<dim3(256), dim3(64), 0, stream>>>(W_o, 295, 39, 256, W_o, 295, 0, 39, wbo, 320);
    if (use_fb)
        build_fb<<<dim3((E + 3) / 4), dim3(256), 0, stream>>>(fbonds, FB, E);

    const int gE = (E + 63) / 64;     // 3126
    const int gN = (N + 63) / 64;     // 1563

    // layer 0: buf0 = relu(fbonds @ W_i.T)
    if (use_fb)
        fused_layer<<<dim3(gE), dim3(512), 0, stream>>>(
            nullptr, nullptr, 0, FB, 64, 1, nullptr, 0, 0, 0, wbi, 64, nullptr,
            buf0, E, nullptr, nullptr);
    else
        fused_layer<<<dim3(gE), dim3(512), 0, stream>>>(
            nullptr, nullptr, 0, nullptr, 0, 0, fbonds, 50, 50, 1, wbi, 64, nullptr,
            buf0, E, nullptr, nullptr);

    // hidden layers (ping-pong): dst = relu(gather(src)@W_h.T + fbonds@W_i.T)
    u16* src = buf0;
    u16* dst = buf1;
    for (int it = 0; it < DEPTH - 1; ++it) {
        if (use_fb)
            fused_layer<<<dim3(gE), dim3(512), 0, stream>>>(
                src, bgraph, 4, FB, 64, 1, nullptr, 0, 0, 0, wbh, 320, nullptr,
                dst, E, nullptr, nullptr);
        else
            fused_layer<<<dim3(gE), dim3(512), 0, stream>>>(
                src, bgraph, 4, nullptr, 0, 0, fbonds, 50, 50, 1, wbh, 320, nullptr,
                dst, E, nullptr, nullptr);
        u16* tmp = src; src = dst; dst = tmp;
    }
    // after 5 layers: src = buf1 (final message)

    // output layer, FUSED with per-molecule sum: atomicAdd partial sums of
    // relu(gather_a(src)@W_o[:,39:].T + fatoms@W_o[:,:39].T + b_o) into out
    fused_layer<<<dim3(gN), dim3(512), 0, stream>>>(
        src, agraph, 4, nullptr, 0, 0, fatoms, 39, 39, 1, wbo, 320, b_o,
        nullptr, N, mol_ids, out);

    // divide by per-molecule counts
    normalize_out<<<dim3(N_MOLS), dim3(256), 0, stream>>>(mol_ids, out, N);
}